// Round 1
// baseline (269.353 us; speedup 1.0000x reference)
//
#include <hip/hip_runtime.h>

#define TSC_OUT_LEN 16384
#define TSC_ENC_LEN 16368   // 16384 - 16384/1024
#define TSC_ROWS 8          // rows processed per block

typedef float f32x4 __attribute__((ext_vector_type(4)));

// readfirstlane on a float: forces a block/wave-uniform value into an SGPR.
__device__ __forceinline__ float tsc_rfl(float x) {
    return __uint_as_float(__builtin_amdgcn_readfirstlane(__float_as_uint(x)));
}

// One row's worth of per-thread input coefficients (10 loads for 8 outputs).
struct TscLd {
    float4 d1;                       // e=1 coeffs (4 outputs per coeff pair)
    float2 d2;                       // e=2 coeffs
    float  c3;                       // e=3 coeff
    float  c4, c5, c6, c7, c8;      // e=4..8 coeffs (per-thread / few-way shared)
    float  c9, c10;                  // e=9,10 coeffs (wave-uniform -> scalar loads)
};

// out[b,j] = sum_{e=1..10} data[b, off_e + (j>>e)] * weights[(2^e-1) + (j&(2^e-1))] + sum_e bias[e-1]
//
// Structure: each block owns a fixed 2048-wide output column tile and loops over
// TSC_ROWS rows. Since j0 is fixed per thread, ALL weight values are loop
// invariant: e=1..3 weights are block-uniform (SGPRs via readfirstlane),
// e=4..10 weights live in 56 VGPRs, loaded once from an LDS staging copy
// (shifted +1 so the 8-long runs starting at 2^e-1 are 16B aligned).
// Steady-state loop: 10 global loads + 80 FMAs + 2 NT stores per 8 outputs,
// software-pipelined 2 deep; no LDS access, no barriers.
__global__ __launch_bounds__(256) void tsc_transpose_kernel(
    const float* __restrict__ data,
    const float* __restrict__ weights,
    const float* __restrict__ bias,
    float* __restrict__ out)
{
    __shared__ float wl[2048];
    const int tid = threadIdx.x;
    for (int i = tid; i < 2047; i += 256) wl[i + 1] = weights[i];
    __syncthreads();

    const int tile = blockIdx.x & 7;           // output column tile (0..7)
    const int rg   = blockIdx.x >> 3;          // row group (0..B/TSC_ROWS)
    const int j0   = (tile << 11) + (tid << 3);  // fixed 8-aligned output column

    // Sum of all per-scale biases — one constant added to every output.
    float bs = 0.0f;
#pragma unroll
    for (int i = 0; i < 10; ++i) bs += bias[i];

    // e=1..3 weights: identical for every thread in the block -> SGPRs.
    const float w1a = tsc_rfl(wl[2]), w1b = tsc_rfl(wl[3]);
    const float w2a = tsc_rfl(wl[4]), w2b = tsc_rfl(wl[5]);
    const float w2c = tsc_rfl(wl[6]), w2d = tsc_rfl(wl[7]);
    float w3[8];
#pragma unroll
    for (int i = 0; i < 8; ++i) w3[i] = tsc_rfl(wl[8 + i]);

    // e=4..10 weights: fixed per thread, register-resident (7 x 8 floats).
    float4 wa[7], wb[7];
#pragma unroll
    for (int e = 4; e <= 10; ++e) {
        const int w  = 1 << e;
        const int kb = w + (j0 & (w - 1));   // 8-aligned -> 16B-aligned LDS reads
        wa[e - 4] = *reinterpret_cast<const float4*>(&wl[kb]);
        wb[e - 4] = *reinterpret_cast<const float4*>(&wl[kb + 4]);
    }

    // Loop-invariant per-lane element offsets into a data row.
    const int i1 = (j0 >> 1);                  // float4, 16B aligned
    const int i2 = 8192  + (j0 >> 2);          // float2, 8B aligned
    const int i3 = 12288 + (j0 >> 3);
    const int i4 = 14336 + (j0 >> 4);
    const int i5 = 15360 + (j0 >> 5);
    const int i6 = 15872 + (j0 >> 6);
    const int i7 = 16128 + (j0 >> 7);
    const int i8 = 16256 + (j0 >> 8);
    // e=9,10 indices are wave-uniform: readfirstlane makes them provably scalar
    // so the addresses become SGPR -> s_load (frees VMEM slots + VGPRs).
    const int i9  = 16320 + __builtin_amdgcn_readfirstlane(j0 >> 9);
    const int i10 = 16352 + __builtin_amdgcn_readfirstlane(j0 >> 10);

    const float* drow = data + (size_t)rg * TSC_ROWS * TSC_ENC_LEN;
    float*       orow = out  + (size_t)rg * TSC_ROWS * TSC_OUT_LEN + j0;

    auto issue = [&](const float* dp, TscLd& L) {
        L.d1  = *reinterpret_cast<const float4*>(dp + i1);
        L.d2  = *reinterpret_cast<const float2*>(dp + i2);
        L.c3  = dp[i3];
        L.c4  = dp[i4];
        L.c5  = dp[i5];
        L.c6  = dp[i6];
        L.c7  = dp[i7];
        L.c8  = dp[i8];
        L.c9  = dp[i9];
        L.c10 = dp[i10];
    };

    auto compute_store = [&](const TscLd& L, float* op) {
        float a0 = bs, a1 = bs, a2 = bs, a3 = bs;
        float a4 = bs, a5 = bs, a6 = bs, a7 = bs;
        // e = 1
        a0 = fmaf(L.d1.x, w1a, a0); a1 = fmaf(L.d1.x, w1b, a1);
        a2 = fmaf(L.d1.y, w1a, a2); a3 = fmaf(L.d1.y, w1b, a3);
        a4 = fmaf(L.d1.z, w1a, a4); a5 = fmaf(L.d1.z, w1b, a5);
        a6 = fmaf(L.d1.w, w1a, a6); a7 = fmaf(L.d1.w, w1b, a7);
        // e = 2
        a0 = fmaf(L.d2.x, w2a, a0); a1 = fmaf(L.d2.x, w2b, a1);
        a2 = fmaf(L.d2.x, w2c, a2); a3 = fmaf(L.d2.x, w2d, a3);
        a4 = fmaf(L.d2.y, w2a, a4); a5 = fmaf(L.d2.y, w2b, a5);
        a6 = fmaf(L.d2.y, w2c, a6); a7 = fmaf(L.d2.y, w2d, a7);
        // e = 3
        a0 = fmaf(L.c3, w3[0], a0); a1 = fmaf(L.c3, w3[1], a1);
        a2 = fmaf(L.c3, w3[2], a2); a3 = fmaf(L.c3, w3[3], a3);
        a4 = fmaf(L.c3, w3[4], a4); a5 = fmaf(L.c3, w3[5], a5);
        a6 = fmaf(L.c3, w3[6], a6); a7 = fmaf(L.c3, w3[7], a7);
        // e = 4..10
#define TSC_E(c, i) \
        a0 = fmaf(c, wa[i].x, a0); a1 = fmaf(c, wa[i].y, a1); \
        a2 = fmaf(c, wa[i].z, a2); a3 = fmaf(c, wa[i].w, a3); \
        a4 = fmaf(c, wb[i].x, a4); a5 = fmaf(c, wb[i].y, a5); \
        a6 = fmaf(c, wb[i].z, a6); a7 = fmaf(c, wb[i].w, a7);
        TSC_E(L.c4, 0)
        TSC_E(L.c5, 1)
        TSC_E(L.c6, 2)
        TSC_E(L.c7, 3)
        TSC_E(L.c8, 4)
        TSC_E(L.c9, 5)
        TSC_E(L.c10, 6)
#undef TSC_E
        // Nontemporal: output is never re-read; keep L2/L3 for the input.
        f32x4 v0 = {a0, a1, a2, a3};
        f32x4 v1 = {a4, a5, a6, a7};
        __builtin_nontemporal_store(v0, reinterpret_cast<f32x4*>(op));
        __builtin_nontemporal_store(v1, reinterpret_cast<f32x4*>(op) + 1);
    };

    // 2-deep software pipeline over rows: next row's loads in flight while the
    // current row's FMAs retire.
    TscLd L0, L1;
    issue(drow, L0);
    for (int r = 0; r < TSC_ROWS; r += 2) {
        issue(drow + TSC_ENC_LEN, L1);
        compute_store(L0, orow);
        if (r + 2 < TSC_ROWS) issue(drow + 2 * TSC_ENC_LEN, L0);
        compute_store(L1, orow + TSC_OUT_LEN);
        drow += 2 * TSC_ENC_LEN;
        orow += 2 * TSC_OUT_LEN;
    }
}

extern "C" void kernel_launch(void* const* d_in, const int* in_sizes, int n_in,
                              void* d_out, int out_size, void* d_ws, size_t ws_size,
                              hipStream_t stream) {
    const float* data    = (const float*)d_in[0];
    const float* weights = (const float*)d_in[1];
    const float* bias    = (const float*)d_in[2];
    float* out = (float*)d_out;

    const int B = in_sizes[0] / TSC_ENC_LEN;   // 2048
    dim3 grid((B / TSC_ROWS) * 8);             // 8 column tiles x 256 row groups = 2048
    dim3 block(256);
    tsc_transpose_kernel<<<grid, block, 0, stream>>>(data, weights, bias, out);
}

// Round 2
// 245.905 us; speedup vs baseline: 1.0954x; 1.0954x over previous
//
#include <hip/hip_runtime.h>

#define TSC_OUT_LEN 16384
#define TSC_ENC_LEN 16368   // 16384 - 16384/1024
#define TSC_ROWS 16         // rows processed per block

// readfirstlane on a float: forces a block/wave-uniform value into an SGPR.
__device__ __forceinline__ float tsc_rfl(float x) {
    return __uint_as_float(__builtin_amdgcn_readfirstlane(__float_as_uint(x)));
}

// One row's worth of per-thread input coefficients (10 loads for 8 outputs).
struct TscLd {
    float4 d1;                       // e=1 coeffs
    float2 d2;                       // e=2 coeffs
    float  c3;                       // e=3 coeff
    float  c4, c5, c6, c7, c8;       // e=4..8 coeffs
    float  c9, c10;                  // e=9,10 coeffs (wave-uniform -> scalar loads)
};

// out[b,j] = sum_{e=1..10} data[b, off_e + (j>>e)] * weights[(2^e-1) + (j&(2^e-1))] + sum_e bias[e-1]
//
// Column-persistent: each block owns a fixed 2048-wide output column tile and
// loops over TSC_ROWS=16 consecutive rows. All weights are loop-invariant:
// e=1..3 block-uniform -> SGPRs, e=4..10 in 56 VGPRs (loaded once from an LDS
// staging copy shifted +1 so runs starting at 2^e-1 are 16B aligned).
// Grid = 1024 blocks = 4 blocks/CU: ALL blocks resident in a single scheduling
// round (VGPR 80 allows 6/CU; launch_bounds(256,4) asks for 4). 16 waves/CU,
// each keeping ~10 loads permanently in flight via a 2-deep row pipeline ->
// continuous HBM read occupancy, no per-row staging, no barriers in loop.
// Plain (cached) stores: NT stores measurably inflated WRITE_SIZE 1.5x in R1.
__global__ __launch_bounds__(256, 4) void tsc_transpose_kernel(
    const float* __restrict__ data,
    const float* __restrict__ weights,
    const float* __restrict__ bias,
    float* __restrict__ out)
{
    __shared__ float wl[2048];
    const int tid = threadIdx.x;
    for (int i = tid; i < 2047; i += 256) wl[i + 1] = weights[i];
    __syncthreads();

    const int tile = blockIdx.x & 7;             // output column tile (0..7)
    const int rg   = blockIdx.x >> 3;            // row group (0..127)
    const int j0   = (tile << 11) + (tid << 3);  // fixed 8-aligned output column

    // Sum of all per-scale biases — one constant added to every output.
    float bs = 0.0f;
#pragma unroll
    for (int i = 0; i < 10; ++i) bs += bias[i];

    // e=1..3 weights: identical for every thread in the block -> SGPRs.
    const float w1a = tsc_rfl(wl[2]), w1b = tsc_rfl(wl[3]);
    const float w2a = tsc_rfl(wl[4]), w2b = tsc_rfl(wl[5]);
    const float w2c = tsc_rfl(wl[6]), w2d = tsc_rfl(wl[7]);
    float w3[8];
#pragma unroll
    for (int i = 0; i < 8; ++i) w3[i] = tsc_rfl(wl[8 + i]);

    // e=4..10 weights: fixed per thread, register-resident (7 x 8 floats).
    float4 wa[7], wb[7];
#pragma unroll
    for (int e = 4; e <= 10; ++e) {
        const int w  = 1 << e;
        const int kb = w + (j0 & (w - 1));   // 8-aligned -> 16B-aligned LDS reads
        wa[e - 4] = *reinterpret_cast<const float4*>(&wl[kb]);
        wb[e - 4] = *reinterpret_cast<const float4*>(&wl[kb + 4]);
    }

    // Loop-invariant per-lane element offsets into a data row.
    const int i1 = (j0 >> 1);                  // float4, 16B aligned
    const int i2 = 8192  + (j0 >> 2);          // float2, 8B aligned
    const int i3 = 12288 + (j0 >> 3);
    const int i4 = 14336 + (j0 >> 4);
    const int i5 = 15360 + (j0 >> 5);
    const int i6 = 15872 + (j0 >> 6);
    const int i7 = 16128 + (j0 >> 7);
    const int i8 = 16256 + (j0 >> 8);
    // e=9,10 indices are wave-uniform: readfirstlane makes them provably scalar.
    const int i9  = 16320 + __builtin_amdgcn_readfirstlane(j0 >> 9);
    const int i10 = 16352 + __builtin_amdgcn_readfirstlane(j0 >> 10);

    const float* drow = data + (size_t)rg * TSC_ROWS * TSC_ENC_LEN;
    float*       orow = out  + (size_t)rg * TSC_ROWS * TSC_OUT_LEN + j0;

    auto issue = [&](const float* dp, TscLd& L) {
        L.d1  = *reinterpret_cast<const float4*>(dp + i1);
        L.d2  = *reinterpret_cast<const float2*>(dp + i2);
        L.c3  = dp[i3];
        L.c4  = dp[i4];
        L.c5  = dp[i5];
        L.c6  = dp[i6];
        L.c7  = dp[i7];
        L.c8  = dp[i8];
        L.c9  = dp[i9];
        L.c10 = dp[i10];
    };

    auto compute_store = [&](const TscLd& L, float* op) {
        float a0 = bs, a1 = bs, a2 = bs, a3 = bs;
        float a4 = bs, a5 = bs, a6 = bs, a7 = bs;
        // e = 1
        a0 = fmaf(L.d1.x, w1a, a0); a1 = fmaf(L.d1.x, w1b, a1);
        a2 = fmaf(L.d1.y, w1a, a2); a3 = fmaf(L.d1.y, w1b, a3);
        a4 = fmaf(L.d1.z, w1a, a4); a5 = fmaf(L.d1.z, w1b, a5);
        a6 = fmaf(L.d1.w, w1a, a6); a7 = fmaf(L.d1.w, w1b, a7);
        // e = 2
        a0 = fmaf(L.d2.x, w2a, a0); a1 = fmaf(L.d2.x, w2b, a1);
        a2 = fmaf(L.d2.x, w2c, a2); a3 = fmaf(L.d2.x, w2d, a3);
        a4 = fmaf(L.d2.y, w2a, a4); a5 = fmaf(L.d2.y, w2b, a5);
        a6 = fmaf(L.d2.y, w2c, a6); a7 = fmaf(L.d2.y, w2d, a7);
        // e = 3
        a0 = fmaf(L.c3, w3[0], a0); a1 = fmaf(L.c3, w3[1], a1);
        a2 = fmaf(L.c3, w3[2], a2); a3 = fmaf(L.c3, w3[3], a3);
        a4 = fmaf(L.c3, w3[4], a4); a5 = fmaf(L.c3, w3[5], a5);
        a6 = fmaf(L.c3, w3[6], a6); a7 = fmaf(L.c3, w3[7], a7);
        // e = 4..10
#define TSC_E(c, i) \
        a0 = fmaf(c, wa[i].x, a0); a1 = fmaf(c, wa[i].y, a1); \
        a2 = fmaf(c, wa[i].z, a2); a3 = fmaf(c, wa[i].w, a3); \
        a4 = fmaf(c, wb[i].x, a4); a5 = fmaf(c, wb[i].y, a5); \
        a6 = fmaf(c, wb[i].z, a6); a7 = fmaf(c, wb[i].w, a7);
        TSC_E(L.c4, 0)
        TSC_E(L.c5, 1)
        TSC_E(L.c6, 2)
        TSC_E(L.c7, 3)
        TSC_E(L.c8, 4)
        TSC_E(L.c9, 5)
        TSC_E(L.c10, 6)
#undef TSC_E
        float4* o4 = reinterpret_cast<float4*>(op);
        o4[0] = make_float4(a0, a1, a2, a3);
        o4[1] = make_float4(a4, a5, a6, a7);
    };

    // 2-deep software pipeline over rows: next row's loads in flight while the
    // current row's FMAs retire. Keep the loop rolled (I-cache friendly); the
    // pipeline overlap is within the 2-row body.
    TscLd L0, L1;
    issue(drow, L0);
#pragma unroll 1
    for (int r = 0; r < TSC_ROWS; r += 2) {
        issue(drow + TSC_ENC_LEN, L1);
        compute_store(L0, orow);
        if (r + 2 < TSC_ROWS) issue(drow + 2 * TSC_ENC_LEN, L0);
        compute_store(L1, orow + TSC_OUT_LEN);
        drow += 2 * TSC_ENC_LEN;
        orow += 2 * TSC_OUT_LEN;
    }
}

extern "C" void kernel_launch(void* const* d_in, const int* in_sizes, int n_in,
                              void* d_out, int out_size, void* d_ws, size_t ws_size,
                              hipStream_t stream) {
    const float* data    = (const float*)d_in[0];
    const float* weights = (const float*)d_in[1];
    const float* bias    = (const float*)d_in[2];
    float* out = (float*)d_out;

    const int B = in_sizes[0] / TSC_ENC_LEN;   // 2048
    dim3 grid((B / TSC_ROWS) * 8);             // 8 column tiles x 128 row groups = 1024
    dim3 block(256);
    tsc_transpose_kernel<<<grid, block, 0, stream>>>(data, weights, bias, out);
}